// Round 5
// baseline (106.911 us; speedup 1.0000x reference)
//
#include <hip/hip_runtime.h>
#include <math.h>

#define NP 100
#define NPILLAR 24000
#define OUT_CH 64
#define NTOTAL 2400000.0            // bs*V*P
#define VXc 0.2f
#define VYc 0.2f
#define XOFF 0.1f
#define YOFF (-39.9f)
#define BN_EPS 1e-3
#define G1 1024                     // main-kernel blocks
#define NWAVE1 (G1 * 4)
#define G2 256                      // apply-kernel blocks

typedef __attribute__((ext_vector_type(8))) short bf16x8;
typedef __attribute__((ext_vector_type(16))) float f32x16;
typedef __attribute__((ext_vector_type(4))) unsigned int uint4v;

__device__ __forceinline__ unsigned int f2bf(float x) {
    unsigned int b = __builtin_bit_cast(unsigned int, x);
    b += 0x7FFFu + ((b >> 16) & 1u);   // RNE
    return b >> 16;
}

__device__ __forceinline__ void build_f(const float4 p, float mx, float my, float mz,
                                        float cx, float cy, float* f) {
    f[0] = p.x; f[1] = p.y; f[2] = p.z; f[3] = p.w;
    f[4] = p.x - mx; f[5] = p.y - my; f[6] = p.z - mz;
    f[7] = p.x - cx; f[8] = p.y - cy;
}

__device__ __forceinline__ void moments(float* s, const float* f) {
    int k = 9;
#pragma unroll
    for (int i = 0; i < 9; ++i) {
        s[i] += f[i];
#pragma unroll
        for (int j = i; j < 9; ++j) { s[k] = fmaf(f[i], f[j], s[k]); ++k; }
    }
}

// ---- K1: one feature read: moments + MFMA xmax/xmin (unnormalized) ---------
__global__ __launch_bounds__(256, 3) void pfn_main(
    const float4* __restrict__ feat, const int* __restrict__ npts,
    const int* __restrict__ coors, const float* __restrict__ W,
    float* __restrict__ xmax_ws, float* __restrict__ xmin_ws,
    float* __restrict__ part)
{
    const int tid = threadIdx.x;
    const int lane = tid & 63;
    const int wv = tid >> 6;
    const int gw = blockIdx.x * 4 + wv;

    // B fragments (persistent): lane holds B[k=(lane>>5)*8+i][col(+32)]
    const int col = lane & 31;
    const int kbase = (lane >> 5) * 8;
    const bool lo = (lane < 32);
    bf16x8 bfr0, bfr1;
#pragma unroll
    for (int i = 0; i < 8; ++i) {
        int k = kbase + i;
        float w0 = (k < 9) ? W[k * OUT_CH + col] : 0.f;
        float w1 = (k < 9) ? W[k * OUT_CH + 32 + col] : 0.f;
        bfr0[i] = (short)f2bf(w0);
        bfr1[i] = (short)f2bf(w1);
    }
    f32x16 cz;
#pragma unroll
    for (int i = 0; i < 16; ++i) cz[i] = 0.f;

    float s[54];
#pragma unroll
    for (int i = 0; i < 54; ++i) s[i] = 0.f;

    for (int pv = gw; pv < NPILLAR; pv += NWAVE1) {
        const float4* fp = feat + (size_t)pv * NP;
        float4 p0 = fp[lane];
        float4 p1 = (lane + 64 < NP) ? fp[lane + 64] : make_float4(0.f, 0.f, 0.f, 0.f);

        float sx = p0.x + p1.x, sy = p0.y + p1.y, sz = p0.z + p1.z;
#pragma unroll
        for (int off = 32; off; off >>= 1) {
            sx += __shfl_xor(sx, off);
            sy += __shfl_xor(sy, off);
            sz += __shfl_xor(sz, off);
        }
        int np_ = npts[pv];
        if (np_ > NP) np_ = NP;
        float inv = 1.f / fmaxf((float)np_, 1.f);
        float mx = sx * inv, my = sy * inv, mz = sz * inv;
        float cx = (float)coors[pv * 4 + 2] * VXc + XOFF;
        float cy = (float)coors[pv * 4 + 1] * VYc + YOFF;

        unsigned int A[5], B[5];
        {
            float f[9];
            if (lane < np_) {
                build_f(p0, mx, my, mz, cx, cy, f);
                moments(s, f);
                A[0] = f2bf(f[0]) | (f2bf(f[1]) << 16);
                A[1] = f2bf(f[2]) | (f2bf(f[3]) << 16);
                A[2] = f2bf(f[4]) | (f2bf(f[5]) << 16);
                A[3] = f2bf(f[6]) | (f2bf(f[7]) << 16);
                A[4] = f2bf(f[8]);
            } else {
#pragma unroll
                for (int i = 0; i < 5; ++i) A[i] = 0u;
            }
            if (lane + 64 < np_) {
                build_f(p1, mx, my, mz, cx, cy, f);
                moments(s, f);
                B[0] = f2bf(f[0]) | (f2bf(f[1]) << 16);
                B[1] = f2bf(f[2]) | (f2bf(f[3]) << 16);
                B[2] = f2bf(f[4]) | (f2bf(f[5]) << 16);
                B[3] = f2bf(f[6]) | (f2bf(f[7]) << 16);
                B[4] = f2bf(f[8]);
            } else {
#pragma unroll
                for (int i = 0; i < 5; ++i) B[i] = 0u;
            }
        }

        float xmx0 = -INFINITY, xmx1 = -INFINITY;
        float xmn0 = INFINITY, xmn1 = INFINITY;
        const int nmt = (np_ + 31) >> 5;

        for (int mt = 0; mt < nmt; ++mt) {
            const int src = ((mt & 1) << 5) + col;
            unsigned int w0, w1, w2, w3, w4;
            if (mt < 2) {
                w0 = __shfl((int)A[0], src); w1 = __shfl((int)A[1], src);
                w2 = __shfl((int)A[2], src); w3 = __shfl((int)A[3], src);
                w4 = __shfl((int)A[4], src);
            } else {
                w0 = __shfl((int)B[0], src); w1 = __shfl((int)B[1], src);
                w2 = __shfl((int)B[2], src); w3 = __shfl((int)B[3], src);
                w4 = __shfl((int)B[4], src);
            }
            uint4v av = {lo ? w0 : w4, lo ? w1 : 0u, lo ? w2 : 0u, lo ? w3 : 0u};
            bf16x8 afr = __builtin_bit_cast(bf16x8, av);

            f32x16 c0 = __builtin_amdgcn_mfma_f32_32x32x16_bf16(afr, bfr0, cz, 0, 0, 0);
#pragma unroll
            for (int r = 0; r < 16; r += 2) {       // v_max3-fusable pairs
                xmx0 = fmaxf(xmx0, fmaxf(c0[r], c0[r + 1]));
                xmn0 = fminf(xmn0, fminf(c0[r], c0[r + 1]));
            }
            f32x16 c1 = __builtin_amdgcn_mfma_f32_32x32x16_bf16(afr, bfr1, cz, 0, 0, 0);
#pragma unroll
            for (int r = 0; r < 16; r += 2) {
                xmx1 = fmaxf(xmx1, fmaxf(c1[r], c1[r + 1]));
                xmn1 = fminf(xmn1, fminf(c1[r], c1[r + 1]));
            }
        }

        // padded positions always exist (np <= 99): x = 0 participates
        xmx0 = fmaxf(xmx0, 0.f); xmx1 = fmaxf(xmx1, 0.f);
        xmn0 = fminf(xmn0, 0.f); xmn1 = fminf(xmn1, 0.f);

        xmx0 = fmaxf(xmx0, __shfl_xor(xmx0, 32));
        xmx1 = fmaxf(xmx1, __shfl_xor(xmx1, 32));
        xmn0 = fminf(xmn0, __shfl_xor(xmn0, 32));
        xmn1 = fminf(xmn1, __shfl_xor(xmn1, 32));

        xmax_ws[(size_t)pv * OUT_CH + lane] = lo ? xmx0 : xmx1;
        xmin_ws[(size_t)pv * OUT_CH + lane] = lo ? xmn0 : xmn1;
    }

    // block-level moment partials
#pragma unroll
    for (int i = 0; i < 54; ++i) {
#pragma unroll
        for (int off = 32; off; off >>= 1) s[i] += __shfl_xor(s[i], off);
    }
    __shared__ float red[4][54];
    if (lane == 0) {
#pragma unroll
        for (int i = 0; i < 54; ++i) red[wv][i] = s[i];
    }
    __syncthreads();
    if (tid < 64) {
        float v = 0.f;
        if (tid < 54)
            v = red[0][tid] + red[1][tid] + red[2][tid] + red[3][tid];
        part[(size_t)blockIdx.x * 64 + tid] = v;   // block-major
    }
}

// ---- K2: redundant partial reduce + scale/shift + apply affine+relu --------
__global__ __launch_bounds__(256) void pfn_apply(
    const float* __restrict__ part, const float* __restrict__ W,
    const float* __restrict__ gamma, const float* __restrict__ beta,
    const float4* __restrict__ xmax_ws, const float4* __restrict__ xmin_ws,
    float4* __restrict__ out)
{
    __shared__ double dred[4][64];
    __shared__ double dm[64];
    __shared__ float sc_s[64], sh_s[64];

    const int t = threadIdx.x;
    const int m = t & 63;
    const int g = t >> 6;

    double s = 0.0;
    for (int b = g; b < G1; b += 4)
        s += (double)part[(size_t)b * 64 + m];
    dred[g][m] = s;
    __syncthreads();

    if (t < 64) {
        dm[t] = dred[0][t] + dred[1][t] + dred[2][t] + dred[3][t];
    }
    __syncthreads();

    if (t < 64) {
        double w[9];
#pragma unroll
        for (int i = 0; i < 9; ++i) w[i] = (double)W[i * OUT_CH + t];
        double mean = 0.0;
#pragma unroll
        for (int i = 0; i < 9; ++i) mean += dm[i] * w[i];
        mean /= NTOTAL;
        double ex2 = 0.0;
        int k = 9;
#pragma unroll
        for (int i = 0; i < 9; ++i) {
#pragma unroll
            for (int j = i; j < 9; ++j) {
                ex2 += (i == j ? 1.0 : 2.0) * dm[k] * w[i] * w[j];
                ++k;
            }
        }
        ex2 /= NTOTAL;
        double var = ex2 - mean * mean;
        double scale = (double)gamma[t] / sqrt(var + BN_EPS);
        double shift = (double)beta[t] - mean * scale;
        sc_s[t] = (float)scale;
        sh_s[t] = (float)shift;
    }
    __syncthreads();

    const int N4 = NPILLAR * OUT_CH / 4;   // 384000 float4
    for (int i = blockIdx.x * 256 + t; i < N4; i += G2 * 256) {
        float4 mx = xmax_ws[i];
        float4 mn = xmin_ws[i];
        int c = (i & 15) * 4;
        float4 r;
        {
            float sc = sc_s[c + 0], sh = sh_s[c + 0];
            r.x = fmaxf(fmaf(sc, (sc >= 0.f) ? mx.x : mn.x, sh), 0.f);
        }
        {
            float sc = sc_s[c + 1], sh = sh_s[c + 1];
            r.y = fmaxf(fmaf(sc, (sc >= 0.f) ? mx.y : mn.y, sh), 0.f);
        }
        {
            float sc = sc_s[c + 2], sh = sh_s[c + 2];
            r.z = fmaxf(fmaf(sc, (sc >= 0.f) ? mx.z : mn.z, sh), 0.f);
        }
        {
            float sc = sc_s[c + 3], sh = sh_s[c + 3];
            r.w = fmaxf(fmaf(sc, (sc >= 0.f) ? mx.w : mn.w, sh), 0.f);
        }
        out[i] = r;
    }
}

extern "C" void kernel_launch(void* const* d_in, const int* in_sizes, int n_in,
                              void* d_out, int out_size, void* d_ws, size_t ws_size,
                              hipStream_t stream) {
    const float4* feat = (const float4*)d_in[0];
    const int* npts    = (const int*)d_in[1];
    const int* coors   = (const int*)d_in[2];
    const float* W     = (const float*)d_in[3];
    const float* gamma = (const float*)d_in[4];
    const float* beta  = (const float*)d_in[5];

    float* xmax_ws = (float*)d_ws;                        // 24000*64 f32
    float* xmin_ws = xmax_ws + (size_t)NPILLAR * OUT_CH;  // 24000*64 f32
    float* part    = xmin_ws + (size_t)NPILLAR * OUT_CH;  // 1024*64 f32

    pfn_main<<<G1, 256, 0, stream>>>(feat, npts, coors, W, xmax_ws, xmin_ws, part);
    pfn_apply<<<G2, 256, 0, stream>>>(part, W, gamma, beta,
                                      (const float4*)xmax_ws, (const float4*)xmin_ws,
                                      (float4*)d_out);
}

// Round 7
// 57.503 us; speedup vs baseline: 1.8592x; 1.8592x over previous
//
#include <hip/hip_runtime.h>
#include <math.h>

#define NP 100
#define NPILLAR 24000
#define OUT_CH 64
#define NTOTAL 2400000.0            // bs*V*P
#define VXc 0.2f
#define VYc 0.2f
#define XOFF 0.1f
#define YOFF (-39.9f)
#define BN_EPS 1e-3
#define G1 768                      // stats blocks (3/CU)
#define NW1 (G1 * 4)
#define G2 1024                     // apply blocks (4/CU)
#define NW2 (G2 * 4)

typedef __attribute__((ext_vector_type(8))) short bf16x8;
typedef __attribute__((ext_vector_type(16))) float f32x16;
typedef __attribute__((ext_vector_type(4))) unsigned int uint4v;

__device__ __forceinline__ unsigned int f2bf(float x) {
    unsigned int b = __builtin_bit_cast(unsigned int, x);
    b += 0x7FFFu + ((b >> 16) & 1u);   // RNE
    return b >> 16;
}

__device__ __forceinline__ unsigned int pk2(float a, float b) {
    return f2bf(a) | (f2bf(b) << 16);
}

__device__ __forceinline__ void build_f(const float4 p, float mx, float my, float mz,
                                        float cx, float cy, float* f) {
    f[0] = p.x; f[1] = p.y; f[2] = p.z; f[3] = p.w;
    f[4] = p.x - mx; f[5] = p.y - my; f[6] = p.z - mz;
    f[7] = p.x - cx; f[8] = p.y - cy;
}

__device__ __forceinline__ void moments(float* s, const float* f) {
    int k = 9;
#pragma unroll
    for (int i = 0; i < 9; ++i) {
        s[i] += f[i];
#pragma unroll
        for (int j = i; j < 9; ++j) { s[k] = fmaf(f[i], f[j], s[k]); ++k; }
    }
}

// ---- K1: moments of the 9-dim augmented feature + per-pillar meta ----------
__global__ __launch_bounds__(256, 4) void pfn_stats(
    const float4* __restrict__ feat, const int* __restrict__ npts,
    const int* __restrict__ coors, float4* __restrict__ meta,
    double* __restrict__ tot)
{
    const int tid = threadIdx.x;
    const int lane = tid & 63;
    const int wv = tid >> 6;
    const int gw = blockIdx.x * 4 + wv;

    float s[54];
#pragma unroll
    for (int i = 0; i < 54; ++i) s[i] = 0.f;

    for (int pv = gw; pv < NPILLAR; pv += NW1) {
        const float4* fp = feat + (size_t)pv * NP;
        float4 p0 = fp[lane];
        float4 p1 = (lane + 64 < NP) ? fp[lane + 64] : make_float4(0.f, 0.f, 0.f, 0.f);

        float sx = p0.x + p1.x, sy = p0.y + p1.y, sz = p0.z + p1.z;
#pragma unroll
        for (int off = 32; off; off >>= 1) {
            sx += __shfl_xor(sx, off);
            sy += __shfl_xor(sy, off);
            sz += __shfl_xor(sz, off);
        }
        int np_ = npts[pv];
        if (np_ > NP) np_ = NP;
        float inv = 1.f / fmaxf((float)np_, 1.f);
        float mx = sx * inv, my = sy * inv, mz = sz * inv;
        float cx = (float)coors[pv * 4 + 2] * VXc + XOFF;
        float cy = (float)coors[pv * 4 + 1] * VYc + YOFF;
        if (lane == 0) {
            meta[2 * pv]     = make_float4(mx, my, mz, __int_as_float(np_));
            meta[2 * pv + 1] = make_float4(cx, cy, 0.f, 0.f);
        }

        float f[9];
        if (lane < np_) {
            build_f(p0, mx, my, mz, cx, cy, f);
            moments(s, f);
        }
        if (lane + 64 < np_) {
            build_f(p1, mx, my, mz, cx, cy, f);
            moments(s, f);
        }
    }

#pragma unroll
    for (int i = 0; i < 54; ++i) {
#pragma unroll
        for (int off = 32; off; off >>= 1) s[i] += __shfl_xor(s[i], off);
    }
    __shared__ float red[4][54];
    if (lane == 0) {
#pragma unroll
        for (int i = 0; i < 54; ++i) red[wv][i] = s[i];
    }
    __syncthreads();
    if (tid < 54) {
        atomicAdd(&tot[tid],
                  (double)(red[0][tid] + red[1][tid] + red[2][tid] + red[3][tid]));
    }
}

// ---- K2: scale/shift from moments, scale folded into B, MFMA max, output ---
__global__ __launch_bounds__(256, 4) void pfn_apply(
    const float4* __restrict__ feat, const float4* __restrict__ meta,
    const double* __restrict__ tot, const float* __restrict__ W,
    const float* __restrict__ gamma, const float* __restrict__ beta,
    float* __restrict__ out)
{
    const int tid = threadIdx.x;
    const int lane = tid & 63;
    const int wv = tid >> 6;
    const int gw = blockIdx.x * 4 + wv;

    __shared__ float sc_s[64], sh_s[64];

    // per-block: BN scale/shift per channel (double, from finished moments)
    if (tid < 64) {
        double w[9];
#pragma unroll
        for (int i = 0; i < 9; ++i) w[i] = (double)W[i * OUT_CH + tid];
        double mean = 0.0;
#pragma unroll
        for (int i = 0; i < 9; ++i) mean += tot[i] * w[i];
        mean /= NTOTAL;
        double ex2 = 0.0;
        int k = 9;
#pragma unroll
        for (int i = 0; i < 9; ++i) {
#pragma unroll
            for (int j = i; j < 9; ++j) {
                ex2 += (i == j ? 1.0 : 2.0) * tot[k] * w[i] * w[j];
                ++k;
            }
        }
        ex2 /= NTOTAL;
        double var = ex2 - mean * mean;
        double scale = (double)gamma[tid] / sqrt(var + BN_EPS);
        double shift = (double)beta[tid] - mean * scale;
        sc_s[tid] = (float)scale;
        sh_s[tid] = (float)shift;
    }
    __syncthreads();

    // B fragments with scale folded in: C = scale * x  (max always, no min)
    const int col = lane & 31;
    const int kbase = (lane >> 5) * 8;
    const bool lo = (lane < 32);
    const float scv0 = sc_s[col];
    const float scv1 = sc_s[col + 32];
    uint4v bu0, bu1;
#pragma unroll
    for (int i = 0; i < 4; ++i) {
        int k0 = kbase + 2 * i, k1 = kbase + 2 * i + 1;
        float a0 = (k0 < 9) ? W[k0 * OUT_CH + col] * scv0 : 0.f;
        float a1 = (k1 < 9) ? W[k1 * OUT_CH + col] * scv0 : 0.f;
        float b0 = (k0 < 9) ? W[k0 * OUT_CH + 32 + col] * scv1 : 0.f;
        float b1 = (k1 < 9) ? W[k1 * OUT_CH + 32 + col] * scv1 : 0.f;
        bu0[i] = pk2(a0, a1);
        bu1[i] = pk2(b0, b1);
    }
    const bf16x8 bfr0 = __builtin_bit_cast(bf16x8, bu0);
    const bf16x8 bfr1 = __builtin_bit_cast(bf16x8, bu1);
    f32x16 cz;
#pragma unroll
    for (int i = 0; i < 16; ++i) cz[i] = 0.f;
    const float sh = sh_s[lane];

    for (int pv = gw; pv < NPILLAR; pv += NW2) {
        const float4* fp = feat + (size_t)pv * NP;
        float4 p0 = fp[lane];
        float4 p1 = (lane + 64 < NP) ? fp[lane + 64] : make_float4(0.f, 0.f, 0.f, 0.f);
        float4 m1 = meta[2 * pv];
        float4 m2 = meta[2 * pv + 1];
        const float mx = m1.x, my = m1.y, mz = m1.z;
        const int np_ = __float_as_int(m1.w);
        const float cx = m2.x, cy = m2.y;

        unsigned int A[5], B[5];
        {
            float f[9];
            if (lane < np_) {
                build_f(p0, mx, my, mz, cx, cy, f);
                A[0] = pk2(f[0], f[1]); A[1] = pk2(f[2], f[3]);
                A[2] = pk2(f[4], f[5]); A[3] = pk2(f[6], f[7]);
                A[4] = pk2(f[8], 0.f);
            } else {
#pragma unroll
                for (int i = 0; i < 5; ++i) A[i] = 0u;
            }
            if (lane + 64 < np_) {
                build_f(p1, mx, my, mz, cx, cy, f);
                B[0] = pk2(f[0], f[1]); B[1] = pk2(f[2], f[3]);
                B[2] = pk2(f[4], f[5]); B[3] = pk2(f[6], f[7]);
                B[4] = pk2(f[8], 0.f);
            } else {
#pragma unroll
                for (int i = 0; i < 5; ++i) B[i] = 0u;
            }
        }

        // padded x=0 rows always exist (np <= 99) -> init running max at 0
        float xm0 = 0.f, xm1 = 0.f;
        const int nmt = (np_ + 31) >> 5;

        for (int mt = 0; mt < nmt; ++mt) {
            const int src = ((mt & 1) << 5) + col;
            unsigned int w0, w1, w2, w3, w4;
            if (mt < 2) {
                w0 = __shfl((int)A[0], src); w1 = __shfl((int)A[1], src);
                w2 = __shfl((int)A[2], src); w3 = __shfl((int)A[3], src);
                w4 = __shfl((int)A[4], src);
            } else {
                w0 = __shfl((int)B[0], src); w1 = __shfl((int)B[1], src);
                w2 = __shfl((int)B[2], src); w3 = __shfl((int)B[3], src);
                w4 = __shfl((int)B[4], src);
            }
            uint4v av = {lo ? w0 : w4, lo ? w1 : 0u, lo ? w2 : 0u, lo ? w3 : 0u};
            bf16x8 afr = __builtin_bit_cast(bf16x8, av);

            f32x16 c0 = __builtin_amdgcn_mfma_f32_32x32x16_bf16(afr, bfr0, cz, 0, 0, 0);
#pragma unroll
            for (int r = 0; r < 16; r += 2)          // v_max3-fusable
                xm0 = fmaxf(xm0, fmaxf(c0[r], c0[r + 1]));
            f32x16 c1 = __builtin_amdgcn_mfma_f32_32x32x16_bf16(afr, bfr1, cz, 0, 0, 0);
#pragma unroll
            for (int r = 0; r < 16; r += 2)
                xm1 = fmaxf(xm1, fmaxf(c1[r], c1[r + 1]));
        }

        xm0 = fmaxf(xm0, __shfl_xor(xm0, 32));
        xm1 = fmaxf(xm1, __shfl_xor(xm1, 32));

        out[(size_t)pv * OUT_CH + lane] = fmaxf((lo ? xm0 : xm1) + sh, 0.f);
    }
}

extern "C" void kernel_launch(void* const* d_in, const int* in_sizes, int n_in,
                              void* d_out, int out_size, void* d_ws, size_t ws_size,
                              hipStream_t stream) {
    const float4* feat = (const float4*)d_in[0];
    const int* npts    = (const int*)d_in[1];
    const int* coors   = (const int*)d_in[2];
    const float* W     = (const float*)d_in[3];
    const float* gamma = (const float*)d_in[4];
    const float* beta  = (const float*)d_in[5];

    double* tot  = (double*)d_ws;                         // 54 doubles
    float4* meta = (float4*)((char*)d_ws + 512);          // 2*24000 float4

    (void)hipMemsetAsync(tot, 0, 54 * sizeof(double), stream);  // atomics start at 0 every call
    pfn_stats<<<G1, 256, 0, stream>>>(feat, npts, coors, meta, tot);
    pfn_apply<<<G2, 256, 0, stream>>>(feat, meta, tot, W, gamma, beta, (float*)d_out);
}